// Round 4
// baseline (272.304 us; speedup 1.0000x reference)
//
#include <hip/hip_runtime.h>

// ---------------------------------------------------------------------------
// TopKPooling (PyG-style) fused pipeline for MI355X.
// G=256 graphs, N=2048 nodes/graph, D=128, E=4194304, DE=16, k=1024.
//
// Outputs (concatenated flat float32 in d_out):
//   x_out [G*k,128] | edge_index_out [2,E] | edge_attr_out [E,16]
//   batch_out [G*k] | edge_mask [E]
//
// Ordering correctness: top-k rank must match the f64 numpy reference.
// tanh(dot/||w||) is monotone in dot, so the f64 dot IS the sort key.
// The f32 gate value only scales x_out (huge absmax threshold) -> tanhf.
// ---------------------------------------------------------------------------

// K0: one wave computes 1/||w|| once (kills the per-node wsq reduce).
__global__ void norm_kernel(const float* __restrict__ w,
                            float* __restrict__ inv_norm) {
  int l = threadIdx.x;  // 64 threads
  float2 wv = reinterpret_cast<const float2*>(w)[l];
  float s = wv.x * wv.x + wv.y * wv.y;
#pragma unroll
  for (int off = 32; off > 0; off >>= 1) s += __shfl_xor(s, off);
  if (l == 0) *inv_norm = __frsqrt_rn(s);
}

// K1: 16 lanes per node row (2x float4/lane), 4 rows per wave.
// f64 dot = sort key; f32 gate = tanhf(dot * inv_norm).
// 4 shuffle levels (f64) = 8 ds-ops per 32B/lane -> LDS pipe fully hidden.
__global__ __launch_bounds__(256) void score_kernel(
    const float* __restrict__ x, const float* __restrict__ w,
    const float* __restrict__ inv_norm, double* __restrict__ keys,
    float* __restrict__ gate, int n_total) {
  int t = (int)(blockIdx.x * 256u + threadIdx.x);
  int row = t >> 4;
  int sub = t & 15;
  if (row >= n_total) return;
  const float4* xp = reinterpret_cast<const float4*>(x + (size_t)row * 128 + sub * 8);
  const float4* wp = reinterpret_cast<const float4*>(w + sub * 8);
  float4 a = xp[0], b = xp[1];
  float4 wa = wp[0], wb = wp[1];
  double dot = (double)a.x * wa.x + (double)a.y * wa.y +
               (double)a.z * wa.z + (double)a.w * wa.w +
               (double)b.x * wb.x + (double)b.y * wb.y +
               (double)b.z * wb.z + (double)b.w * wb.w;
#pragma unroll
  for (int off = 8; off > 0; off >>= 1) dot += __shfl_xor(dot, off);
  if (sub == 0) {
    keys[row] = dot;
    gate[row] = tanhf((float)dot * inv_norm[0]);
  }
}

// K2: per-graph bitonic full sort of 2048 f64 keys (descending, ties->low idx).
// LDS index padded j -> j + (j>>4) to break power-of-2 bank strides
// (unpadded stride-1 stages are systematic 8-way conflicts on u64 keys).
#define TK_PAD(j) ((j) + ((j) >> 4))
__global__ __launch_bounds__(1024) void topk_kernel(
    const double* __restrict__ keys, int* __restrict__ perm,
    int* __restrict__ node_map, int n, int k) {
  __shared__ unsigned long long skey[2048 + 128];
  __shared__ int sidx[2048 + 128];
  const int g = blockIdx.x;
  const int tid = threadIdx.x;

  for (int j = tid; j < n; j += 1024) {
    unsigned long long b =
        (unsigned long long)__double_as_longlong(keys[(size_t)g * n + j]);
    // monotone double->u64, inverted: ascending u64 == descending score
    unsigned long long u = (b & 0x8000000000000000ULL) ? ~b : (b | 0x8000000000000000ULL);
    skey[TK_PAD(j)] = ~u;
    sidx[TK_PAD(j)] = j;
  }

  for (int size = 2; size <= n; size <<= 1) {
    for (int stride = size >> 1; stride > 0; stride >>= 1) {
      __syncthreads();
      int lo = ((tid & ~(stride - 1)) << 1) | (tid & (stride - 1));
      int hi = lo + stride;
      bool asc = ((lo & size) == 0);
      int plo = TK_PAD(lo), phi = TK_PAD(hi);
      unsigned long long ka = skey[plo], kb = skey[phi];
      int ia = sidx[plo], ib = sidx[phi];
      bool hi_lt_lo = (kb < ka) || (kb == ka && ib < ia);
      bool lo_lt_hi = (ka < kb) || (ka == kb && ia < ib);
      if (asc ? hi_lt_lo : lo_lt_hi) {
        skey[plo] = kb; skey[phi] = ka;
        sidx[plo] = ib; sidx[phi] = ia;
      }
    }
  }
  __syncthreads();

  for (int r = tid; r < n; r += 1024) {
    int node = g * n + sidx[TK_PAD(r)];
    node_map[node] = (r < k) ? (g * k + r) : -1;
    if (r < k) perm[g * k + r] = node;
  }
}

// K3: x_out[row] = x[perm[row]] * gate[perm[row]]; batch_out.
__global__ __launch_bounds__(256) void gather_kernel(
    const float* __restrict__ x, const float* __restrict__ gate,
    const int* __restrict__ perm, float* __restrict__ x_out,
    float* __restrict__ batch_out, int total_rows, int k) {
  int t = (int)(blockIdx.x * 256u + threadIdx.x);
  int row = t >> 5;
  int d4 = t & 31;
  if (row >= total_rows) return;
  int src = perm[row];
  float s = gate[src];
  float4 v = *reinterpret_cast<const float4*>(x + (size_t)src * 128 + d4 * 4);
  v.x *= s; v.y *= s; v.z *= s; v.w *= s;
  *reinterpret_cast<float4*>(x_out + (size_t)row * 128 + d4 * 4) = v;
  if (d4 == 0) batch_out[row] = (float)(row / k);
}

// K4: fused edge remap + mask + attr gating, block-tiled for coalescing.
// Phase A: 256 threads -> 256 edge masks (coalesced idx reads, LDS mask).
// Phase B: 256 threads stream the block's 1024 float4 attrs contiguously.
__global__ __launch_bounds__(256) void edge_kernel(
    const int* __restrict__ edge_index, const int* __restrict__ node_map,
    const float4* __restrict__ attr, float* __restrict__ eio,
    float* __restrict__ mask_out, float4* __restrict__ attr_out, int E) {
  __shared__ float smask[256];
  const int base = (int)(blockIdx.x * 256u);
  const int e = base + threadIdx.x;
  int ns = node_map[edge_index[e]];
  int nd = node_map[edge_index[E + e]];
  bool m = (ns >= 0) && (nd >= 0);
  float z = m ? 1.0f : 0.0f;
  eio[e] = m ? (float)ns : -1.0f;
  eio[E + e] = m ? (float)nd : -1.0f;
  mask_out[e] = z;
  smask[threadIdx.x] = z;
  __syncthreads();
  const float4* ablk = attr + (size_t)base * 4;
  float4* oblk = attr_out + (size_t)base * 4;
#pragma unroll
  for (int it = 0; it < 4; ++it) {
    int idx = it * 256 + (int)threadIdx.x;   // 0..1023, lane-contiguous 16B
    float zz = smask[idx >> 2];
    float4 a = ablk[idx];
    a.x *= zz; a.y *= zz; a.z *= zz; a.w *= zz;
    oblk[idx] = a;
  }
}

extern "C" void kernel_launch(void* const* d_in, const int* in_sizes, int n_in,
                              void* d_out, int out_size, void* d_ws, size_t ws_size,
                              hipStream_t stream) {
  const float* x          = (const float*)d_in[0];
  const int*   edge_index = (const int*)d_in[1];
  const float* edge_attr  = (const float*)d_in[2];
  const float* w          = (const float*)d_in[4];

  const int D = 128;
  const int n_total = in_sizes[0] / D;         // 524288
  const int E = in_sizes[1] / 2;               // 4194304
  const int G = 256;
  const int n = n_total / G;                   // 2048
  const int k = (n + 1) / 2;                   // 1024
  const int total_rows = G * k;                // 262144

  float* out       = (float*)d_out;
  float* x_out     = out;
  float* eio       = x_out + (size_t)total_rows * D;
  float* attr_out  = eio + (size_t)2 * E;
  float* batch_out = attr_out + (size_t)E * 16;
  float* mask_out  = batch_out + total_rows;

  double* keys   = (double*)d_ws;                                   // 4 MB
  float* gate    = (float*)((char*)d_ws + (size_t)n_total * 8);     // 2 MB
  int* perm      = (int*)(gate + n_total);                          // 1 MB
  int* node_map  = perm + total_rows;                               // 2 MB
  float* inv_nrm = (float*)(node_map + n_total);

  norm_kernel<<<1, 64, 0, stream>>>(w, inv_nrm);
  score_kernel<<<(n_total * 16) / 256, 256, 0, stream>>>(
      x, w, inv_nrm, keys, gate, n_total);
  topk_kernel<<<G, 1024, 0, stream>>>(keys, perm, node_map, n, k);
  gather_kernel<<<(total_rows * 32) / 256, 256, 0, stream>>>(
      x, gate, perm, x_out, batch_out, total_rows, k);
  edge_kernel<<<E / 256, 256, 0, stream>>>(
      edge_index, node_map, (const float4*)edge_attr, eio, mask_out,
      (float4*)attr_out, E);
}

// Round 5
// 225.682 us; speedup vs baseline: 1.2066x; 1.2066x over previous
//
#include <hip/hip_runtime.h>

// ---------------------------------------------------------------------------
// TopKPooling (PyG-style) fused pipeline for MI355X.
// G=256 graphs, N=2048 nodes/graph, D=128, E=4194304, DE=16, k=1024.
//
// Outputs (concatenated flat float32 in d_out):
//   x_out [G*k,128] | edge_index_out [2,E] | edge_attr_out [E,16]
//   batch_out [G*k] | edge_mask [E]
//
// Ordering correctness: top-k rank must match the f64 numpy reference.
// tanh(dot/||w||) is monotone in dot, so the f64 dot IS the sort key.
// The f32 gate value only scales x_out (huge absmax threshold) -> tanhf,
// recomputed from the f64 key inside the output kernel.
//
// 3 kernels: score -> topk -> merged output (gather blocks + edge blocks).
// Gather blocks take low blockIdx so they dispatch first and re-read x while
// L3 (256 MB ~= |x|) still holds it from score. Stream-once data uses
// nontemporal hints to keep L2/L3 for node_map (random-hit) and x.
// ---------------------------------------------------------------------------

typedef float f32x4_v __attribute__((ext_vector_type(4)));

__device__ inline void nt_store4(float4 v, float4* p) {
  f32x4_v t; t.x = v.x; t.y = v.y; t.z = v.z; t.w = v.w;
  __builtin_nontemporal_store(t, reinterpret_cast<f32x4_v*>(p));
}
__device__ inline float4 nt_load4(const float4* p) {
  f32x4_v t = __builtin_nontemporal_load(reinterpret_cast<const f32x4_v*>(p));
  return make_float4(t.x, t.y, t.z, t.w);
}

// K1: 16 lanes per node row (2x float4/lane), 4 rows per wave.
// f64 dot = sort key (written to keys; gate recomputed later from it).
__global__ __launch_bounds__(256) void score_kernel(
    const float* __restrict__ x, const float* __restrict__ w,
    double* __restrict__ keys, int n_total) {
  int t = (int)(blockIdx.x * 256u + threadIdx.x);
  int row = t >> 4;
  int sub = t & 15;
  if (row >= n_total) return;
  const float4* xp = reinterpret_cast<const float4*>(x + (size_t)row * 128 + sub * 8);
  const float4* wp = reinterpret_cast<const float4*>(w + sub * 8);
  float4 a = xp[0], b = xp[1];
  float4 wa = wp[0], wb = wp[1];
  double dot = (double)a.x * wa.x + (double)a.y * wa.y +
               (double)a.z * wa.z + (double)a.w * wa.w +
               (double)b.x * wb.x + (double)b.y * wb.y +
               (double)b.z * wb.z + (double)b.w * wb.w;
#pragma unroll
  for (int off = 8; off > 0; off >>= 1) dot += __shfl_xor(dot, off);
  if (sub == 0) keys[row] = dot;
}

// K2: per-graph bitonic full sort of 2048 f64 keys (descending, ties->low idx).
#define TK_PAD(j) ((j) + ((j) >> 4))
__global__ __launch_bounds__(1024) void topk_kernel(
    const double* __restrict__ keys, int* __restrict__ perm,
    int* __restrict__ node_map, int n, int k) {
  __shared__ unsigned long long skey[2048 + 128];
  __shared__ int sidx[2048 + 128];
  const int g = blockIdx.x;
  const int tid = threadIdx.x;

  for (int j = tid; j < n; j += 1024) {
    unsigned long long b =
        (unsigned long long)__double_as_longlong(keys[(size_t)g * n + j]);
    // monotone double->u64, inverted: ascending u64 == descending score
    unsigned long long u = (b & 0x8000000000000000ULL) ? ~b : (b | 0x8000000000000000ULL);
    skey[TK_PAD(j)] = ~u;
    sidx[TK_PAD(j)] = j;
  }

  for (int size = 2; size <= n; size <<= 1) {
    for (int stride = size >> 1; stride > 0; stride >>= 1) {
      __syncthreads();
      int lo = ((tid & ~(stride - 1)) << 1) | (tid & (stride - 1));
      int hi = lo + stride;
      bool asc = ((lo & size) == 0);
      int plo = TK_PAD(lo), phi = TK_PAD(hi);
      unsigned long long ka = skey[plo], kb = skey[phi];
      int ia = sidx[plo], ib = sidx[phi];
      bool hi_lt_lo = (kb < ka) || (kb == ka && ib < ia);
      bool lo_lt_hi = (ka < kb) || (ka == kb && ia < ib);
      if (asc ? hi_lt_lo : lo_lt_hi) {
        skey[plo] = kb; skey[phi] = ka;
        sidx[plo] = ib; sidx[phi] = ia;
      }
    }
  }
  __syncthreads();

  for (int r = tid; r < n; r += 1024) {
    int node = g * n + sidx[TK_PAD(r)];
    node_map[node] = (r < k) ? (g * k + r) : -1;
    if (r < k) perm[g * k + r] = node;
  }
}

// K3: merged output kernel.
//   blocks [0, NB_G):      gather 32 rows each (x_out, batch_out)
//   blocks [NB_G, +NB_E):  512 edges each (eio, mask, attr_out)
__global__ __launch_bounds__(256) void output_kernel(
    const float* __restrict__ x, const double* __restrict__ keys,
    const float* __restrict__ w, const int* __restrict__ perm,
    const int* __restrict__ node_map, const int* __restrict__ edge_index,
    const float4* __restrict__ attr, float* __restrict__ x_out,
    float* __restrict__ batch_out, float* __restrict__ eio,
    float* __restrict__ mask_out, float4* __restrict__ attr_out,
    int E, int k, int NB_G) {
  const int bid = (int)blockIdx.x;
  if (bid < NB_G) {
    // ---- gather part ----
    // wave-redundant 1/||w||: 64 lanes x float2, 6 shfl levels
    int l = threadIdx.x & 63;
    float2 wv = reinterpret_cast<const float2*>(w)[l];
    float wsq = wv.x * wv.x + wv.y * wv.y;
#pragma unroll
    for (int off = 32; off > 0; off >>= 1) wsq += __shfl_xor(wsq, off);
    float inv = __frsqrt_rn(wsq);

    int d4 = threadIdx.x & 31;
    int rbase = bid * 32 + ((int)threadIdx.x >> 5);
#pragma unroll
    for (int r4 = 0; r4 < 4; ++r4) {
      int row = rbase + r4 * 8;
      int src = perm[row];
      float s = tanhf((float)keys[src] * inv);
      float4 v = *reinterpret_cast<const float4*>(x + (size_t)src * 128 + d4 * 4);
      v.x *= s; v.y *= s; v.z *= s; v.w *= s;
      nt_store4(v, reinterpret_cast<float4*>(x_out + (size_t)row * 128 + d4 * 4));
      if (d4 == 0)
        __builtin_nontemporal_store((float)(row / k), batch_out + row);
    }
  } else {
    // ---- edge part ----
    __shared__ float smask[256];
    const int ebase = (bid - NB_G) * 512;
    for (int it = 0; it < 2; ++it) {
      int e = ebase + it * 256 + (int)threadIdx.x;
      int s0 = __builtin_nontemporal_load(edge_index + e);
      int s1 = __builtin_nontemporal_load(edge_index + E + e);
      int ns = node_map[s0];
      int nd = node_map[s1];
      bool m = (ns >= 0) && (nd >= 0);
      float z = m ? 1.0f : 0.0f;
      __builtin_nontemporal_store(m ? (float)ns : -1.0f, eio + e);
      __builtin_nontemporal_store(m ? (float)nd : -1.0f, eio + E + e);
      __builtin_nontemporal_store(z, mask_out + e);
      smask[threadIdx.x] = z;
      __syncthreads();
      const float4* ablk = attr + (size_t)(ebase + it * 256) * 4;
      float4* oblk = attr_out + (size_t)(ebase + it * 256) * 4;
#pragma unroll
      for (int j = 0; j < 4; ++j) {
        int idx = j * 256 + (int)threadIdx.x;  // lane-contiguous 16B
        float zz = smask[idx >> 2];
        float4 a = nt_load4(ablk + idx);
        a.x *= zz; a.y *= zz; a.z *= zz; a.w *= zz;
        nt_store4(a, oblk + idx);
      }
      __syncthreads();
    }
  }
}

extern "C" void kernel_launch(void* const* d_in, const int* in_sizes, int n_in,
                              void* d_out, int out_size, void* d_ws, size_t ws_size,
                              hipStream_t stream) {
  const float* x          = (const float*)d_in[0];
  const int*   edge_index = (const int*)d_in[1];
  const float* edge_attr  = (const float*)d_in[2];
  const float* w          = (const float*)d_in[4];

  const int D = 128;
  const int n_total = in_sizes[0] / D;         // 524288
  const int E = in_sizes[1] / 2;               // 4194304
  const int G = 256;
  const int n = n_total / G;                   // 2048
  const int k = (n + 1) / 2;                   // 1024
  const int total_rows = G * k;                // 262144

  float* out       = (float*)d_out;
  float* x_out     = out;
  float* eio       = x_out + (size_t)total_rows * D;
  float* attr_out  = eio + (size_t)2 * E;
  float* batch_out = attr_out + (size_t)E * 16;
  float* mask_out  = batch_out + total_rows;

  double* keys  = (double*)d_ws;                                    // 4 MB
  int* perm     = (int*)((char*)d_ws + (size_t)n_total * 8);        // 1 MB
  int* node_map = perm + total_rows;                                // 2 MB

  score_kernel<<<(n_total * 16) / 256, 256, 0, stream>>>(x, w, keys, n_total);
  topk_kernel<<<G, 1024, 0, stream>>>(keys, perm, node_map, n, k);

  const int NB_G = total_rows / 32;            // 8192 gather blocks
  const int NB_E = E / 512;                    // 8192 edge blocks
  output_kernel<<<NB_G + NB_E, 256, 0, stream>>>(
      x, keys, w, perm, node_map, edge_index, (const float4*)edge_attr,
      x_out, batch_out, eio, mask_out, (float4*)attr_out, E, k, NB_G);
}

// Round 6
// 225.241 us; speedup vs baseline: 1.2089x; 1.0020x over previous
//
#include <hip/hip_runtime.h>

// ---------------------------------------------------------------------------
// TopKPooling (PyG-style) fused pipeline for MI355X.
// G=256 graphs, N=2048 nodes/graph, D=128, E=4194304, DE=16, k=1024.
//
// Outputs (concatenated flat float32 in d_out):
//   x_out [G*k,128] | edge_index_out [2,E] | edge_attr_out [E,16]
//   batch_out [G*k] | edge_mask [E]
//
// Ordering correctness: top-k rank must match the f64 numpy reference.
// tanh(dot/||w||) is monotone in dot, so the f64 dot IS the sort key.
// The f32 gate value only scales x_out (huge absmax threshold) -> tanhf.
//
// 2 kernels:
//   K1: per-graph fused score+sort (block=1024 threads=one graph; dots go
//       straight into LDS sort keys; gate written once per node).
//   K2: merged output (gather blocks + edge blocks). Edge part needs the
//       full node_map (edges span graphs) so the kernel split is the only
//       required global barrier.
// ---------------------------------------------------------------------------

typedef float f32x4_v __attribute__((ext_vector_type(4)));

__device__ inline void nt_store4(float4 v, float4* p) {
  f32x4_v t; t.x = v.x; t.y = v.y; t.z = v.z; t.w = v.w;
  __builtin_nontemporal_store(t, reinterpret_cast<f32x4_v*>(p));
}
__device__ inline float4 nt_load4(const float4* p) {
  f32x4_v t = __builtin_nontemporal_load(reinterpret_cast<const f32x4_v*>(p));
  return make_float4(t.x, t.y, t.z, t.w);
}

#define TK_PAD(j) ((j) + ((j) >> 4))

// K1: one block per graph. 16-lane groups compute f64 dots (2x float4/lane),
// keys transformed into LDS; bitonic full sort (descending, ties->low idx);
// writes gate, perm, node_map.
__global__ __launch_bounds__(1024) void score_topk_kernel(
    const float* __restrict__ x, const float* __restrict__ w,
    float* __restrict__ gate, int* __restrict__ perm,
    int* __restrict__ node_map, int n, int k) {
  __shared__ unsigned long long skey[2048 + 128];
  __shared__ int sidx[2048 + 128];
  const int g = blockIdx.x;
  const int tid = threadIdx.x;

  // per-wave 1/||w|| (w is 512B, L1-hot; redundant across 16 waves)
  {
    int l = tid & 63;
    float2 wv2 = reinterpret_cast<const float2*>(w)[l];
    float wsq = wv2.x * wv2.x + wv2.y * wv2.y;
#pragma unroll
    for (int off = 32; off > 0; off >>= 1) wsq += __shfl_xor(wsq, off);
    float inv = __frsqrt_rn(wsq);

    const int grp = tid >> 4;  // 64 groups of 16 lanes
    const int sub = tid & 15;
    const float4* wp = reinterpret_cast<const float4*>(w + sub * 8);
    const float4 wa = wp[0], wb = wp[1];
    const float* xg = x + (size_t)g * n * 128;

#pragma unroll 2
    for (int r0 = grp; r0 < n; r0 += 64) {
      const float4* xp =
          reinterpret_cast<const float4*>(xg + (size_t)r0 * 128 + sub * 8);
      float4 a = xp[0], b = xp[1];
      double dot = (double)a.x * wa.x + (double)a.y * wa.y +
                   (double)a.z * wa.z + (double)a.w * wa.w +
                   (double)b.x * wb.x + (double)b.y * wb.y +
                   (double)b.z * wb.z + (double)b.w * wb.w;
#pragma unroll
      for (int off = 8; off > 0; off >>= 1) dot += __shfl_xor(dot, off);
      if (sub == 0) {
        unsigned long long bb = (unsigned long long)__double_as_longlong(dot);
        // monotone double->u64, inverted: ascending u64 == descending score
        unsigned long long u =
            (bb & 0x8000000000000000ULL) ? ~bb : (bb | 0x8000000000000000ULL);
        skey[TK_PAD(r0)] = ~u;
        sidx[TK_PAD(r0)] = r0;
        gate[g * n + r0] = tanhf((float)dot * inv);
      }
    }
  }

  for (int size = 2; size <= n; size <<= 1) {
    for (int stride = size >> 1; stride > 0; stride >>= 1) {
      __syncthreads();
      int lo = ((tid & ~(stride - 1)) << 1) | (tid & (stride - 1));
      int hi = lo + stride;
      bool asc = ((lo & size) == 0);
      int plo = TK_PAD(lo), phi = TK_PAD(hi);
      unsigned long long ka = skey[plo], kb = skey[phi];
      int ia = sidx[plo], ib = sidx[phi];
      bool hi_lt_lo = (kb < ka) || (kb == ka && ib < ia);
      bool lo_lt_hi = (ka < kb) || (ka == kb && ia < ib);
      if (asc ? hi_lt_lo : lo_lt_hi) {
        skey[plo] = kb; skey[phi] = ka;
        sidx[plo] = ib; sidx[phi] = ia;
      }
    }
  }
  __syncthreads();

  for (int r = tid; r < n; r += 1024) {
    int node = g * n + sidx[TK_PAD(r)];
    node_map[node] = (r < k) ? (g * k + r) : -1;
    if (r < k) perm[g * k + r] = node;
  }
}

// K2: merged output kernel.
//   blocks [0, NB_G):      gather 32 rows each (x_out, batch_out)
//   blocks [NB_G, +NB_E):  512 edges each (eio, mask, attr_out)
__global__ __launch_bounds__(256) void output_kernel(
    const float* __restrict__ x, const float* __restrict__ gate,
    const int* __restrict__ perm, const int* __restrict__ node_map,
    const int* __restrict__ edge_index, const float4* __restrict__ attr,
    float* __restrict__ x_out, float* __restrict__ batch_out,
    float* __restrict__ eio, float* __restrict__ mask_out,
    float4* __restrict__ attr_out, int E, int k, int NB_G) {
  const int bid = (int)blockIdx.x;
  if (bid < NB_G) {
    // ---- gather part ----
    int d4 = threadIdx.x & 31;
    int rbase = bid * 32 + ((int)threadIdx.x >> 5);
#pragma unroll
    for (int r4 = 0; r4 < 4; ++r4) {
      int row = rbase + r4 * 8;
      int src = perm[row];
      float s = gate[src];
      float4 v = *reinterpret_cast<const float4*>(x + (size_t)src * 128 + d4 * 4);
      v.x *= s; v.y *= s; v.z *= s; v.w *= s;
      nt_store4(v, reinterpret_cast<float4*>(x_out + (size_t)row * 128 + d4 * 4));
      if (d4 == 0)
        __builtin_nontemporal_store((float)(row / k), batch_out + row);
    }
  } else {
    // ---- edge part ----
    __shared__ float smask[256];
    const int ebase = (bid - NB_G) * 512;
    for (int it = 0; it < 2; ++it) {
      int e = ebase + it * 256 + (int)threadIdx.x;
      int s0 = __builtin_nontemporal_load(edge_index + e);
      int s1 = __builtin_nontemporal_load(edge_index + E + e);
      int ns = node_map[s0];
      int nd = node_map[s1];
      bool m = (ns >= 0) && (nd >= 0);
      float z = m ? 1.0f : 0.0f;
      __builtin_nontemporal_store(m ? (float)ns : -1.0f, eio + e);
      __builtin_nontemporal_store(m ? (float)nd : -1.0f, eio + E + e);
      __builtin_nontemporal_store(z, mask_out + e);
      smask[threadIdx.x] = z;
      __syncthreads();
      const float4* ablk = attr + (size_t)(ebase + it * 256) * 4;
      float4* oblk = attr_out + (size_t)(ebase + it * 256) * 4;
#pragma unroll
      for (int j = 0; j < 4; ++j) {
        int idx = j * 256 + (int)threadIdx.x;  // lane-contiguous 16B
        float zz = smask[idx >> 2];
        float4 a = nt_load4(ablk + idx);
        a.x *= zz; a.y *= zz; a.z *= zz; a.w *= zz;
        nt_store4(a, oblk + idx);
      }
      __syncthreads();
    }
  }
}

extern "C" void kernel_launch(void* const* d_in, const int* in_sizes, int n_in,
                              void* d_out, int out_size, void* d_ws, size_t ws_size,
                              hipStream_t stream) {
  const float* x          = (const float*)d_in[0];
  const int*   edge_index = (const int*)d_in[1];
  const float* edge_attr  = (const float*)d_in[2];
  const float* w          = (const float*)d_in[4];

  const int D = 128;
  const int n_total = in_sizes[0] / D;         // 524288
  const int E = in_sizes[1] / 2;               // 4194304
  const int G = 256;
  const int n = n_total / G;                   // 2048
  const int k = (n + 1) / 2;                   // 1024
  const int total_rows = G * k;                // 262144

  float* out       = (float*)d_out;
  float* x_out     = out;
  float* eio       = x_out + (size_t)total_rows * D;
  float* attr_out  = eio + (size_t)2 * E;
  float* batch_out = attr_out + (size_t)E * 16;
  float* mask_out  = batch_out + total_rows;

  float* gate   = (float*)d_ws;                                     // 2 MB
  int* perm     = (int*)(gate + n_total);                           // 1 MB
  int* node_map = perm + total_rows;                                // 2 MB

  score_topk_kernel<<<G, 1024, 0, stream>>>(x, w, gate, perm, node_map, n, k);

  const int NB_G = total_rows / 32;            // 8192 gather blocks
  const int NB_E = E / 512;                    // 8192 edge blocks
  output_kernel<<<NB_G + NB_E, 256, 0, stream>>>(
      x, gate, perm, node_map, edge_index, (const float4*)edge_attr,
      x_out, batch_out, eio, mask_out, (float4*)attr_out, E, k, NB_G);
}

// Round 7
// 222.265 us; speedup vs baseline: 1.2251x; 1.0134x over previous
//
#include <hip/hip_runtime.h>

// ---------------------------------------------------------------------------
// TopKPooling (PyG-style) fused pipeline for MI355X.
// G=256 graphs, N=2048 nodes/graph, D=128, E=4194304, DE=16, k=1024.
//
// Outputs (concatenated flat float32 in d_out):
//   x_out [G*k,128] | edge_index_out [2,E] | edge_attr_out [E,16]
//   batch_out [G*k] | edge_mask [E]
//
// Ordering correctness: top-k rank must match the f64 numpy reference.
// tanh(dot/||w||) is monotone in dot, so the f64 dot IS the sort key.
// The f32 gate value only scales x_out (huge absmax threshold) -> tanhf.
//
// 2 kernels:
//   K1 (one 1024-thread block per graph): score -> LDS bitonic sort ->
//       node_map + IN-KERNEL gather (x_out, batch_out). The block just
//       streamed its 1 MB x-slice, so the gather re-read is L3/L2-hot.
//       gate and perm never leave the block (LDS only).
//   K2: pure edge stream: remap via node_map, mask, gate attrs.
// ---------------------------------------------------------------------------

typedef float f32x4_v __attribute__((ext_vector_type(4)));

__device__ inline void nt_store4(float4 v, float4* p) {
  f32x4_v t; t.x = v.x; t.y = v.y; t.z = v.z; t.w = v.w;
  __builtin_nontemporal_store(t, reinterpret_cast<f32x4_v*>(p));
}
__device__ inline float4 nt_load4(const float4* p) {
  f32x4_v t = __builtin_nontemporal_load(reinterpret_cast<const f32x4_v*>(p));
  return make_float4(t.x, t.y, t.z, t.w);
}

#define TK_PAD(j) ((j) + ((j) >> 4))

// K1: one block per graph. Score (16-lane groups, 2x float4/lane) ->
// bitonic full sort of 2048 f64-derived keys (descending, ties->low idx) ->
// node_map write + gather epilogue.
__global__ __launch_bounds__(1024) void score_topk_gather_kernel(
    const float* __restrict__ x, const float* __restrict__ w,
    int* __restrict__ node_map, float* __restrict__ x_out,
    float* __restrict__ batch_out, int n, int k) {
  __shared__ unsigned long long skey[2048 + 128];
  __shared__ int sidx[2048 + 128];
  __shared__ float gate_lds[2048];
  const int g = blockIdx.x;
  const int tid = threadIdx.x;
  const float* xg = x + (size_t)g * n * 128;

  // ---- score phase ----
  {
    int l = tid & 63;
    float2 wv2 = reinterpret_cast<const float2*>(w)[l];
    float wsq = wv2.x * wv2.x + wv2.y * wv2.y;
#pragma unroll
    for (int off = 32; off > 0; off >>= 1) wsq += __shfl_xor(wsq, off);
    float inv = __frsqrt_rn(wsq);

    const int grp = tid >> 4;  // 64 groups of 16 lanes
    const int sub = tid & 15;
    const float4* wp = reinterpret_cast<const float4*>(w + sub * 8);
    const float4 wa = wp[0], wb = wp[1];

#pragma unroll 2
    for (int r0 = grp; r0 < n; r0 += 64) {
      const float4* xp =
          reinterpret_cast<const float4*>(xg + (size_t)r0 * 128 + sub * 8);
      float4 a = xp[0], b = xp[1];
      double dot = (double)a.x * wa.x + (double)a.y * wa.y +
                   (double)a.z * wa.z + (double)a.w * wa.w +
                   (double)b.x * wb.x + (double)b.y * wb.y +
                   (double)b.z * wb.z + (double)b.w * wb.w;
#pragma unroll
      for (int off = 8; off > 0; off >>= 1) dot += __shfl_xor(dot, off);
      if (sub == 0) {
        unsigned long long bb = (unsigned long long)__double_as_longlong(dot);
        // monotone double->u64, inverted: ascending u64 == descending score
        unsigned long long u =
            (bb & 0x8000000000000000ULL) ? ~bb : (bb | 0x8000000000000000ULL);
        skey[TK_PAD(r0)] = ~u;
        sidx[TK_PAD(r0)] = r0;
        gate_lds[r0] = tanhf((float)dot * inv);
      }
    }
  }

  // ---- bitonic sort ----
  for (int size = 2; size <= n; size <<= 1) {
    for (int stride = size >> 1; stride > 0; stride >>= 1) {
      __syncthreads();
      int lo = ((tid & ~(stride - 1)) << 1) | (tid & (stride - 1));
      int hi = lo + stride;
      bool asc = ((lo & size) == 0);
      int plo = TK_PAD(lo), phi = TK_PAD(hi);
      unsigned long long ka = skey[plo], kb = skey[phi];
      int ia = sidx[plo], ib = sidx[phi];
      bool hi_lt_lo = (kb < ka) || (kb == ka && ib < ia);
      bool lo_lt_hi = (ka < kb) || (ka == kb && ia < ib);
      if (asc ? hi_lt_lo : lo_lt_hi) {
        skey[plo] = kb; skey[phi] = ka;
        sidx[plo] = ib; sidx[phi] = ia;
      }
    }
  }
  __syncthreads();

  // ---- node_map + batch_out ----
  for (int r = tid; r < n; r += 1024) {
    int sl = sidx[TK_PAD(r)];
    node_map[g * n + sl] = (r < k) ? (g * k + r) : -1;
    if (r < k) __builtin_nontemporal_store((float)g, batch_out + g * k + r);
  }
  // sidx/gate_lds are read-only below; no further LDS writes -> no barrier
  // needed for correctness of this thread's reads (values written pre-sort
  // barrier), but reads of sidx written by other threads in the sort need
  // the __syncthreads above (already done).

  // ---- gather epilogue: rank r -> row g*k+r, source row sidx[r] ----
  const int d4 = tid & 31;
  const int rr = tid >> 5;  // 0..31
  float* xo = x_out + (size_t)g * k * 128;
#pragma unroll 2
  for (int it = 0; it < 32; ++it) {
    int r = it * 32 + rr;                 // rank < k = 1024
    int sl = sidx[TK_PAD(r)];             // broadcast within 32-lane group
    float s = gate_lds[sl];               // broadcast
    float4 v = *reinterpret_cast<const float4*>(xg + (size_t)sl * 128 + d4 * 4);
    v.x *= s; v.y *= s; v.z *= s; v.w *= s;
    nt_store4(v, reinterpret_cast<float4*>(xo + (size_t)r * 128 + d4 * 4));
  }
}

// K2: pure edge stream. 512 edges per block.
__global__ __launch_bounds__(256) void edge_kernel(
    const int* __restrict__ edge_index, const int* __restrict__ node_map,
    const float4* __restrict__ attr, float* __restrict__ eio,
    float* __restrict__ mask_out, float4* __restrict__ attr_out, int E) {
  __shared__ float smask[256];
  const int ebase = (int)blockIdx.x * 512;
  for (int it = 0; it < 2; ++it) {
    int e = ebase + it * 256 + (int)threadIdx.x;
    int s0 = __builtin_nontemporal_load(edge_index + e);
    int s1 = __builtin_nontemporal_load(edge_index + E + e);
    int ns = node_map[s0];
    int nd = node_map[s1];
    bool m = (ns >= 0) && (nd >= 0);
    float z = m ? 1.0f : 0.0f;
    __builtin_nontemporal_store(m ? (float)ns : -1.0f, eio + e);
    __builtin_nontemporal_store(m ? (float)nd : -1.0f, eio + E + e);
    __builtin_nontemporal_store(z, mask_out + e);
    smask[threadIdx.x] = z;
    __syncthreads();
    const float4* ablk = attr + (size_t)(ebase + it * 256) * 4;
    float4* oblk = attr_out + (size_t)(ebase + it * 256) * 4;
#pragma unroll
    for (int j = 0; j < 4; ++j) {
      int idx = j * 256 + (int)threadIdx.x;  // lane-contiguous 16B
      float zz = smask[idx >> 2];
      float4 a = nt_load4(ablk + idx);
      a.x *= zz; a.y *= zz; a.z *= zz; a.w *= zz;
      nt_store4(a, oblk + idx);
    }
    __syncthreads();
  }
}

extern "C" void kernel_launch(void* const* d_in, const int* in_sizes, int n_in,
                              void* d_out, int out_size, void* d_ws, size_t ws_size,
                              hipStream_t stream) {
  const float* x          = (const float*)d_in[0];
  const int*   edge_index = (const int*)d_in[1];
  const float* edge_attr  = (const float*)d_in[2];
  const float* w          = (const float*)d_in[4];

  const int D = 128;
  const int n_total = in_sizes[0] / D;         // 524288
  const int E = in_sizes[1] / 2;               // 4194304
  const int G = 256;
  const int n = n_total / G;                   // 2048
  const int k = (n + 1) / 2;                   // 1024
  const int total_rows = G * k;                // 262144

  float* out       = (float*)d_out;
  float* x_out     = out;
  float* eio       = x_out + (size_t)total_rows * D;
  float* attr_out  = eio + (size_t)2 * E;
  float* batch_out = attr_out + (size_t)E * 16;
  float* mask_out  = batch_out + total_rows;

  int* node_map = (int*)d_ws;                                       // 2 MB

  score_topk_gather_kernel<<<G, 1024, 0, stream>>>(
      x, w, node_map, x_out, batch_out, n, k);
  edge_kernel<<<E / 512, 256, 0, stream>>>(
      edge_index, node_map, (const float4*)edge_attr, eio, mask_out,
      (float4*)attr_out, E);
}